// Round 5
// baseline (848.224 us; speedup 1.0000x reference)
//
#include <hip/hip_runtime.h>
#include <math.h>
#include <stdint.h>

#define T_TOTAL 2048
#define NB 16
#define D 256
#define T0 1696      // h buffer covers t in [1696, 2047]
#define TBUF 352
#define TSKIP 1952   // skip needed for t in [1952, 2047]
#define LOUT 96
#define NBLK 256

typedef __bf16 bf16x8 __attribute__((ext_vector_type(8)));
typedef float f32x4 __attribute__((ext_vector_type(4)));

__device__ __forceinline__ void gload_lds16(const void* src, void* lds_dst) {
    auto g = (const __attribute__((address_space(1))) void*)(uintptr_t)src;
    auto l = (__attribute__((address_space(3))) void*)(uintptr_t)(
                 (uint32_t)(uintptr_t)lds_dst);
    __builtin_amdgcn_global_load_lds(g, l, 16, 0, 0);
}

// device-scope grid barrier: monotonic counter, reset by host memset each launch
__device__ __forceinline__ void grid_bar(unsigned* cnt, unsigned target) {
    __builtin_amdgcn_fence(__ATOMIC_RELEASE, "agent");
    __syncthreads();
    if (threadIdx.x == 0) {
        __hip_atomic_fetch_add(cnt, 1u, __ATOMIC_RELAXED, __HIP_MEMORY_SCOPE_AGENT);
        while (__hip_atomic_load(cnt, __ATOMIC_RELAXED, __HIP_MEMORY_SCOPE_AGENT)
               < target)
            __builtin_amdgcn_s_sleep(1);
    }
    __syncthreads();
    __builtin_amdgcn_fence(__ATOMIC_ACQUIRE, "agent");
}

__global__ __launch_bounds__(256, 1) void meganet(
    const float* __restrict__ x_lag, const float* __restrict__ x_cov,
    const float* __restrict__ up_W, const float* __restrict__ up_b,
    const float* __restrict__ dil_w, const float* __restrict__ dil_b_all,
    const float* __restrict__ skip_w, const float* __restrict__ skip_b_all,
    const float* __restrict__ loc_W, const float* __restrict__ loc_b,
    const float* __restrict__ proj_W, const float* __restrict__ proj_b,
    float* __restrict__ out, unsigned* __restrict__ bar,
    float* __restrict__ hf, __bf16* __restrict__ hb,
    __bf16* __restrict__ gated, float* __restrict__ skip,
    __bf16* __restrict__ wT, __bf16* __restrict__ w2)
{
    __shared__ __align__(16) unsigned char lds[49152];
    const int tid = threadIdx.x;
    const int bid = blockIdx.x;
    const int lane = tid & 63, wid = tid >> 6;
    const int wm = wid >> 1, wn = wid & 1;
    const int lr = lane >> 3;
    const int swzc = ((lane & 7) ^ lr) << 3;   // bf16-elem offset, 16B-swizzled
    const int l15 = lane & 15, l4 = lane >> 4;
    unsigned target = 0;

    // ---------------- phase 0: weight prep + up-projection ----------------
    {
        int g = bid * 256 + tid;
        for (int n = g; n < 8 * 512 * 512; n += NBLK * 256) {
            int i = n >> 18, r = n & 262143;
            int co = r >> 9, k = r & 511;
            wT[n] = (__bf16)dil_w[(((size_t)(i << 9) + co) * 256 + (k & 255)) * 2
                                  + (k >> 8)];
        }
        for (int n = g; n < 8 * 512 * 256; n += NBLK * 256)
            w2[n] = (__bf16)skip_w[n];
        for (int row = bid; row < TBUF * NB; row += NBLK) {
            int tt = row >> 4, b = row & 15, t = T0 + tt;
            float acc = up_b[tid] + x_lag[t * NB + b] * up_W[tid];
            const float* cov = &x_cov[(t * NB + b) * 7];
            #pragma unroll
            for (int j = 0; j < 7; ++j)
                acc += cov[j] * up_W[(j + 1) * D + tid];
            size_t idx = ((size_t)row << 8) + tid;
            hf[idx] = acc;
            hb[idx] = (__bf16)acc;
        }
    }
    target += NBLK; grid_bar(bar, target);

    // ---------------- 8 wavenet layers ----------------
    for (int li = 0; li < 8; ++li) {
        const int dil = 1 << li;
        const int tb = T0 + 2 * dil;
        const int M = (T_TOTAL - tb) * NB;
        const int mt = (M + 63) >> 6;
        const __bf16* wTl = wT + (size_t)li * 512 * 512;
        const __bf16* w2l = w2 + (size_t)li * 512 * 256;
        const float* gbias = dil_b_all + li * 512;
        const float* sbias = skip_b_all + li * 512;
        const int roff1 = (tb - T0) * 16;
        const int roff0 = roff1 - dil * 16;

        // -------- gate phase --------
        for (int tile = bid; tile < mt * 4; tile += NBLK) {
            const int m0 = (tile >> 2) << 6;
            const int cb = (tile & 3) << 6;
            f32x4 accf[2][2] = {}; f32x4 accg[2][2] = {};

            auto stage = [&](int t, int buf) {
                const int k0 = t << 6;
                const int ci0 = k0 & 255;
                const int roff = (k0 < 256) ? roff0 : roff1;
                unsigned char* base = lds + buf * 24576;
                #pragma unroll
                for (int j = 0; j < 2; ++j) {
                    int qa = (wid << 1) + j;
                    int m = m0 + (qa << 3) + lr; if (m >= M) m = M - 1;
                    gload_lds16(hb + (size_t)(m + roff) * 256 + ci0 + swzc,
                                base + (qa << 10));
                }
                #pragma unroll
                for (int j = 0; j < 2; ++j) {
                    int qb = (wid << 1) + j;
                    gload_lds16(wTl + (size_t)(cb + (qb << 3) + lr) * 512 + k0 + swzc,
                                base + 8192 + (qb << 10));
                    gload_lds16(wTl + (size_t)(cb + 256 + (qb << 3) + lr) * 512 + k0 + swzc,
                                base + 16384 + (qb << 10));
                }
            };

            stage(0, 0);
            for (int t = 0; t < 8; ++t) {
                const int buf = t & 1;
                if (t < 7) {
                    stage(t + 1, buf ^ 1);
                    asm volatile("s_waitcnt vmcnt(6)" ::: "memory");
                } else {
                    asm volatile("s_waitcnt vmcnt(0)" ::: "memory");
                }
                __builtin_amdgcn_s_barrier();
                const unsigned char* base = lds + buf * 24576;
                #pragma unroll
                for (int ks = 0; ks < 2; ++ks) {
                    const int kb = (ks << 6) + (l4 << 4);
                    bf16x8 av[2], bfv[2], bgv[2];
                    #pragma unroll
                    for (int fm = 0; fm < 2; ++fm) {
                        int r = (wm << 5) + (fm << 4) + l15;
                        av[fm] = *(const bf16x8*)(base + r * 128 + (kb ^ ((r & 7) << 4)));
                    }
                    #pragma unroll
                    for (int fn = 0; fn < 2; ++fn) {
                        int n = (wn << 5) + (fn << 4) + l15;
                        int o = n * 128 + (kb ^ ((n & 7) << 4));
                        bfv[fn] = *(const bf16x8*)(base + 8192 + o);
                        bgv[fn] = *(const bf16x8*)(base + 16384 + o);
                    }
                    #pragma unroll
                    for (int fm = 0; fm < 2; ++fm)
                        #pragma unroll
                        for (int fn = 0; fn < 2; ++fn) {
                            accf[fm][fn] = __builtin_amdgcn_mfma_f32_16x16x32_bf16(
                                av[fm], bfv[fn], accf[fm][fn], 0, 0, 0);
                            accg[fm][fn] = __builtin_amdgcn_mfma_f32_16x16x32_bf16(
                                av[fm], bgv[fn], accg[fm][fn], 0, 0, 0);
                        }
                }
                __builtin_amdgcn_s_barrier();
            }
            #pragma unroll
            for (int fm = 0; fm < 2; ++fm) {
                #pragma unroll
                for (int fn = 0; fn < 2; ++fn) {
                    int c = cb + (wn << 5) + (fn << 4) + l15;
                    float bfb = gbias[c], bgb = gbias[c + 256];
                    #pragma unroll
                    for (int r = 0; r < 4; ++r) {
                        int m = m0 + (wm << 5) + (fm << 4) + (l4 << 2) + r;
                        if (m < M) {
                            float fv = accf[fm][fn][r] + bfb;
                            float gv = accg[fm][fn][r] + bgb;
                            float th = 2.0f / (1.0f + __expf(-2.0f * fv)) - 1.0f;
                            float sg = 1.0f / (1.0f + __expf(-gv));
                            gated[(size_t)m * 256 + c] = (__bf16)(th * sg);
                        }
                    }
                }
            }
        }
        target += NBLK; grid_bar(bar, target);

        // -------- skip phase --------
        for (int tile = bid; tile < mt * 4; tile += NBLK) {
            const int m0 = (tile >> 2) << 6;
            const int cb = (tile & 3) << 6;
            f32x4 acch[2][2] = {}; f32x4 accs[2][2] = {};

            auto stage2 = [&](int t, int buf) {
                const int k0 = t << 6;
                unsigned char* base = lds + buf * 24576;
                #pragma unroll
                for (int j = 0; j < 2; ++j) {
                    int qa = (wid << 1) + j;
                    int m = m0 + (qa << 3) + lr; if (m >= M) m = M - 1;
                    gload_lds16(gated + (size_t)m * 256 + k0 + swzc,
                                base + (qa << 10));
                }
                #pragma unroll
                for (int j = 0; j < 2; ++j) {
                    int qb = (wid << 1) + j;
                    gload_lds16(w2l + (size_t)(cb + (qb << 3) + lr) * 256 + k0 + swzc,
                                base + 8192 + (qb << 10));
                    gload_lds16(w2l + (size_t)(cb + 256 + (qb << 3) + lr) * 256 + k0 + swzc,
                                base + 16384 + (qb << 10));
                }
            };

            stage2(0, 0);
            for (int t = 0; t < 4; ++t) {
                const int buf = t & 1;
                if (t < 3) {
                    stage2(t + 1, buf ^ 1);
                    asm volatile("s_waitcnt vmcnt(6)" ::: "memory");
                } else {
                    asm volatile("s_waitcnt vmcnt(0)" ::: "memory");
                }
                __builtin_amdgcn_s_barrier();
                const unsigned char* base = lds + buf * 24576;
                #pragma unroll
                for (int ks = 0; ks < 2; ++ks) {
                    const int kb = (ks << 6) + (l4 << 4);
                    bf16x8 av[2], bhv[2], bsv[2];
                    #pragma unroll
                    for (int fm = 0; fm < 2; ++fm) {
                        int r = (wm << 5) + (fm << 4) + l15;
                        av[fm] = *(const bf16x8*)(base + r * 128 + (kb ^ ((r & 7) << 4)));
                    }
                    #pragma unroll
                    for (int fn = 0; fn < 2; ++fn) {
                        int n = (wn << 5) + (fn << 4) + l15;
                        int o = n * 128 + (kb ^ ((n & 7) << 4));
                        bhv[fn] = *(const bf16x8*)(base + 8192 + o);
                        bsv[fn] = *(const bf16x8*)(base + 16384 + o);
                    }
                    #pragma unroll
                    for (int fm = 0; fm < 2; ++fm)
                        #pragma unroll
                        for (int fn = 0; fn < 2; ++fn) {
                            acch[fm][fn] = __builtin_amdgcn_mfma_f32_16x16x32_bf16(
                                av[fm], bhv[fn], acch[fm][fn], 0, 0, 0);
                            accs[fm][fn] = __builtin_amdgcn_mfma_f32_16x16x32_bf16(
                                av[fm], bsv[fn], accs[fm][fn], 0, 0, 0);
                        }
                }
                __builtin_amdgcn_s_barrier();
            }
            const int roff = roff1;
            const int ms0 = (TSKIP - tb) * 16;
            const int soff = (tb - TSKIP) * 16;
            #pragma unroll
            for (int fm = 0; fm < 2; ++fm) {
                #pragma unroll
                for (int fn = 0; fn < 2; ++fn) {
                    int c = cb + (wn << 5) + (fn << 4) + l15;
                    float bhb = sbias[c], bsb = sbias[c + 256];
                    #pragma unroll
                    for (int r = 0; r < 4; ++r) {
                        int m = m0 + (wm << 5) + (fm << 4) + (l4 << 2) + r;
                        if (m < M) {
                            size_t hi = (size_t)(m + roff) * 256 + c;
                            float hv = hf[hi] + acch[fm][fn][r] + bhb;
                            hf[hi] = hv;
                            hb[hi] = (__bf16)hv;
                            if (m >= ms0) {
                                size_t si = (size_t)(m + soff) * 256 + c;
                                float sv = accs[fm][fn][r] + bsb;
                                if (li != 0) sv += skip[si];
                                skip[si] = sv;
                            }
                        }
                    }
                }
            }
        }
        target += NBLK; grid_bar(bar, target);
    }

    // ---------------- final ----------------
    for (int grp = bid; grp < (LOUT * NB) / 4; grp += NBLK) {
        int o = grp * 4 + wid;            // o = l*16 + b
        int l = o >> 4, b = o & 15;
        float4 s4 = *(const float4*)&skip[((size_t)o << 8) + (lane << 2)];
        float4 w4 = *(const float4*)&loc_W[lane << 2];
        float s = s4.x * w4.x + s4.y * w4.y + s4.z * w4.z + s4.w * w4.w;
        #pragma unroll
        for (int off = 32; off; off >>= 1) s += __shfl_down(s, off);
        if (lane == 0)
            out[b * LOUT + l] = (s + loc_b[0]) * proj_W[0] + proj_b[0];
    }
}

extern "C" void kernel_launch(void* const* d_in, const int* in_sizes, int n_in,
                              void* d_out, int out_size, void* d_ws, size_t ws_size,
                              hipStream_t stream)
{
    const float* x_lag  = (const float*)d_in[0];
    const float* x_cov  = (const float*)d_in[1];
    const float* up_W   = (const float*)d_in[2];
    const float* up_b   = (const float*)d_in[3];
    const float* dil_w  = (const float*)d_in[4];
    const float* dil_b  = (const float*)d_in[5];
    const float* skip_w = (const float*)d_in[6];
    const float* skip_b = (const float*)d_in[7];
    const float* loc_W  = (const float*)d_in[8];
    const float* loc_b  = (const float*)d_in[9];
    const float* proj_W = (const float*)d_in[10];
    const float* proj_b = (const float*)d_in[11];
    float* out = (float*)d_out;

    unsigned char* ws = (unsigned char*)d_ws;
    unsigned* bar = (unsigned*)ws;                               // 256 B
    float*  hf   = (float*)(ws + 256);                           // 5632*256 f32
    __bf16* hb   = (__bf16*)(ws + 256 + 5767168);                // 5632*256 bf16
    __bf16* gated= (__bf16*)(ws + 256 + 5767168 + 2883584);      // 5632*256 bf16
    float*  skip = (float*)(ws + 256 + 5767168 + 2 * 2883584);   // 1536*256 f32
    __bf16* wT   = (__bf16*)(ws + 256 + 5767168 + 2 * 2883584 + 1572864);
    __bf16* w2   = (__bf16*)((unsigned char*)wT + 4194304);

    (void)hipMemsetAsync(bar, 0, 256, stream);
    hipLaunchKernelGGL(meganet, dim3(NBLK), dim3(256), 0, stream,
                       x_lag, x_cov, up_W, up_b, dil_w, dil_b, skip_w, skip_b,
                       loc_W, loc_b, proj_W, proj_b, out, bar,
                       hf, hb, gated, skip, wT, w2);
}

// Round 6
// 329.468 us; speedup vs baseline: 2.5745x; 2.5745x over previous
//
#include <hip/hip_runtime.h>
#include <math.h>
#include <stdint.h>

#define T_TOTAL 2048
#define NB 16
#define D 256
#define T0 1696      // h buffer covers t in [1696, 2047]
#define TBUF 352
#define TSKIP 1952   // skip needed for t in [1952, 2047]
#define LOUT 96

typedef __bf16 bf16x8 __attribute__((ext_vector_type(8)));
typedef float f32x4 __attribute__((ext_vector_type(4)));

__device__ __forceinline__ void gload_lds16(const void* src, void* lds_dst) {
    auto g = (const __attribute__((address_space(1))) void*)(uintptr_t)src;
    auto l = (__attribute__((address_space(3))) void*)(uintptr_t)(
                 (uint32_t)(uintptr_t)lds_dst);
    __builtin_amdgcn_global_load_lds(g, l, 16, 0, 0);
}

// ---------------- weight prep: wT[i][co][k]=dil_w[i][co][ci][tap] (k=tap*256+ci)
__global__ void prep_w(const float* __restrict__ dil_w,
                       const float* __restrict__ skip_w,
                       __bf16* __restrict__ wT, __bf16* __restrict__ w2)
{
    int n = blockIdx.x * 256 + threadIdx.x;
    if (n < 8 * 512 * 512) {
        int i = n >> 18;
        int r = n & 262143;
        int co = r >> 9, k = r & 511;
        wT[n] = (__bf16)dil_w[(((size_t)(i << 9) + co) * 256 + (k & 255)) * 2 + (k >> 8)];
    } else {
        int n2 = n - 8 * 512 * 512;
        if (n2 < 8 * 512 * 256) w2[n2] = (__bf16)skip_w[n2];
    }
}

// ---------------- up-projection
__global__ void up_kernel(const float* __restrict__ x_lag,
                          const float* __restrict__ x_cov,
                          const float* __restrict__ up_W,
                          const float* __restrict__ up_b,
                          float* __restrict__ hf, __bf16* __restrict__ hb)
{
    int bid = blockIdx.x;          // 0 .. TBUF*NB-1
    int tt  = bid >> 4;
    int b   = bid & 15;
    int t   = T0 + tt;
    int c   = threadIdx.x;         // 0..255
    float acc = up_b[c] + x_lag[t * NB + b] * up_W[c];
    const float* cov = &x_cov[(t * NB + b) * 7];
    #pragma unroll
    for (int j = 0; j < 7; ++j)
        acc += cov[j] * up_W[(j + 1) * D + c];
    size_t idx = ((size_t)bid << 8) + c;
    hf[idx] = acc;
    hb[idx] = (__bf16)acc;
}

// ---------------- fused layer: gate GEMM (K=512) -> LDS -> skip GEMM (K=256)
// block = 512 threads (8 waves), owns 64 output rows.
#define GSTRIDE 264   // gated LDS row stride in bf16 elems (528 B)
__global__ __launch_bounds__(512, 1) void layer_kernel(
    float* __restrict__ hf, __bf16* __restrict__ hb,
    float* __restrict__ skip,
    const __bf16* __restrict__ wTl, const __bf16* __restrict__ w2l,
    const float* __restrict__ gbias, const float* __restrict__ sbias,
    int tb, int dil, int M, int first)
{
    __shared__ __align__(16) unsigned char lds[49152 + 64 * GSTRIDE * 2];
    __bf16* gatedL = (__bf16*)(lds + 49152);
    const int tid = threadIdx.x;
    const int lane = tid & 63, wid = tid >> 6;      // 8 waves
    const int wm = wid >> 2, wn = wid & 3;          // 2 x 4 wave grid
    const int lr = lane >> 3;
    const int swzc = ((lane & 7) ^ lr) << 3;        // bf16-elem, 16B-swizzled
    const int l15 = lane & 15, l4 = lane >> 4;
    const int m0 = blockIdx.x << 6;
    const int roff1 = (tb - T0) * 16;
    const int roff0 = roff1 - dil * 16;

    // ---------------- gate phase: 4 column tiles of 64 ----------------
    #pragma unroll 1
    for (int ct = 0; ct < 4; ++ct) {
        const int cb = ct << 6;
        f32x4 accf[2] = {}, accg[2] = {};

        auto stage = [&](int t, int buf) {
            const int k0 = t << 6;
            const int ci0 = k0 & 255;
            const int roff = (k0 < 256) ? roff0 : roff1;
            unsigned char* base = lds + buf * 24576;
            int m = m0 + (wid << 3) + lr; if (m >= M) m = M - 1;
            gload_lds16(hb + (size_t)(m + roff) * 256 + ci0 + swzc,
                        base + (wid << 10));
            gload_lds16(wTl + (size_t)(cb + (wid << 3) + lr) * 512 + k0 + swzc,
                        base + 8192 + (wid << 10));
            gload_lds16(wTl + (size_t)(cb + 256 + (wid << 3) + lr) * 512 + k0 + swzc,
                        base + 16384 + (wid << 10));
        };

        stage(0, 0);
        for (int t = 0; t < 8; ++t) {
            const int buf = t & 1;
            if (t < 7) {
                stage(t + 1, buf ^ 1);
                asm volatile("s_waitcnt vmcnt(3)" ::: "memory");
            } else {
                asm volatile("s_waitcnt vmcnt(0)" ::: "memory");
            }
            __builtin_amdgcn_s_barrier();
            const unsigned char* base = lds + buf * 24576;
            #pragma unroll
            for (int ks = 0; ks < 2; ++ks) {
                const int kb = (ks << 6) + (l4 << 4);
                bf16x8 av[2], bfv, bgv;
                #pragma unroll
                for (int fm = 0; fm < 2; ++fm) {
                    int r = (wm << 5) + (fm << 4) + l15;
                    av[fm] = *(const bf16x8*)(base + r * 128 + (kb ^ ((r & 7) << 4)));
                }
                {
                    int n = (wn << 4) + l15;
                    int o = n * 128 + (kb ^ ((n & 7) << 4));
                    bfv = *(const bf16x8*)(base + 8192 + o);
                    bgv = *(const bf16x8*)(base + 16384 + o);
                }
                #pragma unroll
                for (int fm = 0; fm < 2; ++fm) {
                    accf[fm] = __builtin_amdgcn_mfma_f32_16x16x32_bf16(
                        av[fm], bfv, accf[fm], 0, 0, 0);
                    accg[fm] = __builtin_amdgcn_mfma_f32_16x16x32_bf16(
                        av[fm], bgv, accg[fm], 0, 0, 0);
                }
            }
            __builtin_amdgcn_s_barrier();
        }
        // activation -> gated LDS
        {
            int c = cb + (wn << 4) + l15;
            float bfb = gbias[c], bgb = gbias[c + 256];
            #pragma unroll
            for (int fm = 0; fm < 2; ++fm)
                #pragma unroll
                for (int r = 0; r < 4; ++r) {
                    int row = (wm << 5) + (fm << 4) + (l4 << 2) + r;
                    float fv = accf[fm][r] + bfb;
                    float gv = accg[fm][r] + bgb;
                    float th = 2.0f / (1.0f + __expf(-2.0f * fv)) - 1.0f;
                    float sg = 1.0f / (1.0f + __expf(-gv));
                    gatedL[row * GSTRIDE + c] = (__bf16)(th * sg);
                }
        }
    }
    __syncthreads();   // gatedL complete

    // ---------------- skip phase: 4 column tiles of 64, K=256 ----------------
    const int ms0 = (TSKIP - tb) * 16;
    const int soff = (tb - TSKIP) * 16;
    #pragma unroll 1
    for (int ct = 0; ct < 4; ++ct) {
        const int cb = ct << 6;
        f32x4 acch[2] = {}, accs[2] = {};

        auto stage2 = [&](int t, int buf) {
            const int k0 = t << 6;
            unsigned char* base = lds + buf * 24576;
            gload_lds16(w2l + (size_t)(cb + (wid << 3) + lr) * 256 + k0 + swzc,
                        base + 8192 + (wid << 10));
            gload_lds16(w2l + (size_t)(cb + 256 + (wid << 3) + lr) * 256 + k0 + swzc,
                        base + 16384 + (wid << 10));
        };

        stage2(0, 0);
        for (int t = 0; t < 4; ++t) {
            const int buf = t & 1;
            if (t < 3) {
                stage2(t + 1, buf ^ 1);
                asm volatile("s_waitcnt vmcnt(2)" ::: "memory");
            } else {
                asm volatile("s_waitcnt vmcnt(0)" ::: "memory");
            }
            __builtin_amdgcn_s_barrier();
            const unsigned char* base = lds + buf * 24576;
            #pragma unroll
            for (int ks = 0; ks < 2; ++ks) {
                const int kb = (ks << 6) + (l4 << 4);
                bf16x8 av[2], bhv, bsv;
                #pragma unroll
                for (int fm = 0; fm < 2; ++fm) {
                    int r = (wm << 5) + (fm << 4) + l15;
                    av[fm] = *(const bf16x8*)&gatedL[r * GSTRIDE + (t << 6) + (ks << 5) + (l4 << 3)];
                }
                {
                    int n = (wn << 4) + l15;
                    int o = n * 128 + (kb ^ ((n & 7) << 4));
                    bhv = *(const bf16x8*)(base + 8192 + o);
                    bsv = *(const bf16x8*)(base + 16384 + o);
                }
                #pragma unroll
                for (int fm = 0; fm < 2; ++fm) {
                    acch[fm] = __builtin_amdgcn_mfma_f32_16x16x32_bf16(
                        av[fm], bhv, acch[fm], 0, 0, 0);
                    accs[fm] = __builtin_amdgcn_mfma_f32_16x16x32_bf16(
                        av[fm], bsv, accs[fm], 0, 0, 0);
                }
            }
            __builtin_amdgcn_s_barrier();
        }
        // epilogue: h += h_next ; skip (+)= skip_next
        {
            int c = cb + (wn << 4) + l15;
            float bhb = sbias[c], bsb = sbias[c + 256];
            #pragma unroll
            for (int fm = 0; fm < 2; ++fm)
                #pragma unroll
                for (int r = 0; r < 4; ++r) {
                    int m = m0 + (wm << 5) + (fm << 4) + (l4 << 2) + r;
                    if (m < M) {
                        size_t hi = (size_t)(m + roff1) * 256 + c;
                        float hv = hf[hi] + acch[fm][r] + bhb;
                        hf[hi] = hv;
                        hb[hi] = (__bf16)hv;
                        if (m >= ms0) {
                            size_t si = (size_t)(m + soff) * 256 + c;
                            float sv = accs[fm][r] + bsb;
                            if (!first) sv += skip[si];
                            skip[si] = sv;
                        }
                    }
                }
        }
    }
}

// ---------------- final
__global__ void final_kernel(const float* __restrict__ skip,
                             const float* __restrict__ loc_W,
                             const float* __restrict__ loc_b,
                             const float* __restrict__ proj_W,
                             const float* __restrict__ proj_b,
                             float* __restrict__ out)
{
    int tid = threadIdx.x;
    int w = tid >> 6, lane = tid & 63;
    int o = blockIdx.x * 4 + w;          // o = l*16 + b
    int l = o >> 4, b = o & 15;
    float4 s4 = *(const float4*)&skip[((size_t)o << 8) + (lane << 2)];
    float4 w4 = *(const float4*)&loc_W[lane << 2];
    float s = s4.x * w4.x + s4.y * w4.y + s4.z * w4.z + s4.w * w4.w;
    #pragma unroll
    for (int off = 32; off; off >>= 1) s += __shfl_down(s, off);
    if (lane == 0)
        out[b * LOUT + l] = (s + loc_b[0]) * proj_W[0] + proj_b[0];
}

extern "C" void kernel_launch(void* const* d_in, const int* in_sizes, int n_in,
                              void* d_out, int out_size, void* d_ws, size_t ws_size,
                              hipStream_t stream)
{
    const float* x_lag  = (const float*)d_in[0];
    const float* x_cov  = (const float*)d_in[1];
    const float* up_W   = (const float*)d_in[2];
    const float* up_b   = (const float*)d_in[3];
    const float* dil_w  = (const float*)d_in[4];
    const float* dil_b  = (const float*)d_in[5];
    const float* skip_w = (const float*)d_in[6];
    const float* skip_b = (const float*)d_in[7];
    const float* loc_W  = (const float*)d_in[8];
    const float* loc_b  = (const float*)d_in[9];
    const float* proj_W = (const float*)d_in[10];
    const float* proj_b = (const float*)d_in[11];
    float* out = (float*)d_out;

    unsigned char* ws = (unsigned char*)d_ws;
    float*  hf   = (float*)ws;                              // 5632*256 f32
    __bf16* hb   = (__bf16*)(ws + 5767168);                 // 5632*256 bf16
    float*  skip = (float*)(ws + 5767168 + 2883584);        // 1536*256 f32
    __bf16* wT   = (__bf16*)(ws + 5767168 + 2883584 + 1572864);  // 8*512*512
    __bf16* w2   = (__bf16*)((unsigned char*)wT + 4194304); // 8*512*256

    hipLaunchKernelGGL(prep_w, dim3(12288), dim3(256), 0, stream,
                       dil_w, skip_w, wT, w2);
    hipLaunchKernelGGL(up_kernel, dim3(TBUF * NB), dim3(D), 0, stream,
                       x_lag, x_cov, up_W, up_b, hf, hb);

    for (int i = 0; i < 8; ++i) {
        int dil = 1 << i;
        int tb  = T0 + 2 * dil;
        int M   = (T_TOTAL - tb) * NB;
        int mt  = (M + 63) >> 6;
        hipLaunchKernelGGL(layer_kernel, dim3(mt), dim3(512), 0, stream,
                           hf, hb, skip,
                           wT + (size_t)i * 512 * 512, w2 + (size_t)i * 512 * 256,
                           dil_b + (size_t)i * 512, skip_b + (size_t)i * 512,
                           tb, dil, M, i == 0 ? 1 : 0);
    }
    hipLaunchKernelGGL(final_kernel, dim3(LOUT * NB / 4), dim3(256), 0, stream,
                       skip, loc_W, loc_b, proj_W, proj_b, out);
}

// Round 7
// 264.955 us; speedup vs baseline: 3.2014x; 1.2435x over previous
//
#include <hip/hip_runtime.h>
#include <math.h>
#include <stdint.h>

#define T_TOTAL 2048
#define NB 16
#define D 256
#define T0 1696      // h buffer covers t in [1696, 2047]
#define TBUF 352
#define TSKIP 1952   // skip needed for t in [1952, 2047]
#define LOUT 96

typedef __bf16 bf16x8 __attribute__((ext_vector_type(8)));
typedef float f32x4 __attribute__((ext_vector_type(4)));

__device__ __forceinline__ void gload_lds16(const void* src, void* lds_dst) {
    auto g = (const __attribute__((address_space(1))) void*)(uintptr_t)src;
    auto l = (__attribute__((address_space(3))) void*)(uintptr_t)(
                 (uint32_t)(uintptr_t)lds_dst);
    __builtin_amdgcn_global_load_lds(g, l, 16, 0, 0);
}

// ---------------- weight prep: wT[i][co][k]=dil_w[i][co][ci][tap] (k=tap*256+ci)
__global__ void prep_w(const float* __restrict__ dil_w,
                       const float* __restrict__ skip_w,
                       __bf16* __restrict__ wT, __bf16* __restrict__ w2)
{
    int n = blockIdx.x * 256 + threadIdx.x;
    if (n < 8 * 512 * 512) {
        int i = n >> 18;
        int r = n & 262143;
        int co = r >> 9, k = r & 511;
        wT[n] = (__bf16)dil_w[(((size_t)(i << 9) + co) * 256 + (k & 255)) * 2 + (k >> 8)];
    } else {
        int n2 = n - 8 * 512 * 512;
        if (n2 < 8 * 512 * 256) w2[n2] = (__bf16)skip_w[n2];
    }
}

// ---------------- up-projection
__global__ void up_kernel(const float* __restrict__ x_lag,
                          const float* __restrict__ x_cov,
                          const float* __restrict__ up_W,
                          const float* __restrict__ up_b,
                          float* __restrict__ hf, __bf16* __restrict__ hb)
{
    int bid = blockIdx.x;          // 0 .. TBUF*NB-1
    int tt  = bid >> 4;
    int b   = bid & 15;
    int t   = T0 + tt;
    int c   = threadIdx.x;         // 0..255
    float acc = up_b[c] + x_lag[t * NB + b] * up_W[c];
    const float* cov = &x_cov[(t * NB + b) * 7];
    #pragma unroll
    for (int j = 0; j < 7; ++j)
        acc += cov[j] * up_W[(j + 1) * D + c];
    size_t idx = ((size_t)bid << 8) + c;
    hf[idx] = acc;
    hb[idx] = (__bf16)acc;
}

// ---------------- GEMM1: full-B-in-LDS once, zero-barrier K-loop
// grid (mt, 4); block 256 thr / 4 waves (2m x 2n); wave: 32 rows x (32f+32g)
__global__ __launch_bounds__(256, 1) void gate_v3(
    const __bf16* __restrict__ hb, __bf16* __restrict__ gated,
    const __bf16* __restrict__ wTl, const float* __restrict__ gbias,
    int tb, int dil, int M)
{
    __shared__ __align__(16) unsigned char lds[131072];  // 128 rows x 1KB
    const int tid = threadIdx.x;
    const int lane = tid & 63, wid = tid >> 6;
    const int wm = wid >> 1, wn = wid & 1;
    const int l15 = lane & 15, l4 = lane >> 4;
    const int m0 = blockIdx.x << 6;
    const int cb = blockIdx.y << 6;       // f col base (0..192)
    const int roff1 = (tb - T0) * 16;
    const int roff0 = roff1 - dil * 16;

    // stage B slice: local rows 0..63 = f cols cb.., 64..127 = g cols 256+cb..
    // swizzled source (elem ^ ((row&7)<<3)), linear LDS dest (row*1024 + lane*16)
    #pragma unroll
    for (int r = wid; r < 128; r += 4) {
        int co = (r < 64) ? (cb + r) : (cb + r + 192);
        gload_lds16(wTl + (size_t)co * 512 + ((lane << 3) ^ ((r & 7) << 3)),
                    lds + (r << 10));
    }
    asm volatile("s_waitcnt vmcnt(0)" ::: "memory");
    __syncthreads();

    f32x4 accf[2][2] = {}, accg[2][2] = {};
    const int rf0 = (wn << 5) + l15;      // local f row of first n-frag
    const int xr  = (l15 & 7) << 3;       // xor term (same for rf0, rf0+16, +64)

    #pragma unroll
    for (int tap = 0; tap < 2; ++tap) {
        const int roff = tap ? roff1 : roff0;
        #pragma unroll
        for (int kk = 0; kk < 8; ++kk) {
            const int k0 = (tap << 8) + (kk << 5);
            const int kx = ((k0 + (l4 << 3)) ^ xr) << 1;   // byte offset in row
            bf16x8 av[2];
            #pragma unroll
            for (int fm = 0; fm < 2; ++fm) {
                int m = m0 + (wm << 5) + (fm << 4) + l15;
                if (m >= M) m = M - 1;
                av[fm] = *(const bf16x8*)(hb + (size_t)(m + roff) * 256
                                          + (kk << 5) + (l4 << 3));
            }
            #pragma unroll
            for (int nf = 0; nf < 2; ++nf) {
                const int rf = rf0 + (nf << 4);
                bf16x8 bf = *(const bf16x8*)(lds + (rf << 10) + kx);
                bf16x8 bg = *(const bf16x8*)(lds + ((rf + 64) << 10) + kx);
                #pragma unroll
                for (int fm = 0; fm < 2; ++fm) {
                    accf[fm][nf] = __builtin_amdgcn_mfma_f32_16x16x32_bf16(
                        av[fm], bf, accf[fm][nf], 0, 0, 0);
                    accg[fm][nf] = __builtin_amdgcn_mfma_f32_16x16x32_bf16(
                        av[fm], bg, accg[fm][nf], 0, 0, 0);
                }
            }
        }
    }

    #pragma unroll
    for (int fm = 0; fm < 2; ++fm)
        #pragma unroll
        for (int nf = 0; nf < 2; ++nf) {
            int c = cb + (wn << 5) + (nf << 4) + l15;
            float bfb = gbias[c], bgb = gbias[c + 256];
            #pragma unroll
            for (int r = 0; r < 4; ++r) {
                int m = m0 + (wm << 5) + (fm << 4) + (l4 << 2) + r;
                if (m < M) {
                    float fv = accf[fm][nf][r] + bfb;
                    float gv = accg[fm][nf][r] + bgb;
                    float th = 2.0f / (1.0f + __expf(-2.0f * fv)) - 1.0f;
                    float sg = 1.0f / (1.0f + __expf(-gv));
                    gated[(size_t)m * 256 + c] = (__bf16)(th * sg);
                }
            }
        }
}

// ---------------- GEMM2: same structure, K=256
__global__ __launch_bounds__(256, 2) void skip_v3(
    const __bf16* __restrict__ gated, const __bf16* __restrict__ w2l,
    float* __restrict__ hf, __bf16* __restrict__ hb,
    float* __restrict__ skip, const float* __restrict__ sbias,
    int tb, int M, int first)
{
    __shared__ __align__(16) unsigned char lds[65536];   // 128 rows x 512B
    const int tid = threadIdx.x;
    const int lane = tid & 63, wid = tid >> 6;
    const int wm = wid >> 1, wn = wid & 1;
    const int l15 = lane & 15, l4 = lane >> 4;
    const int m0 = blockIdx.x << 6;
    const int cb = blockIdx.y << 6;
    const int roff1 = (tb - T0) * 16;

    // stage: two rows per issue (lane>>5 selects row in pair)
    #pragma unroll
    for (int r2 = wid << 1; r2 < 128; r2 += 8) {
        int row = r2 + (lane >> 5);
        int co = (row < 64) ? (cb + row) : (cb + row + 192);
        gload_lds16(w2l + (size_t)co * 256 + (((lane & 31) << 3) ^ ((row & 7) << 3)),
                    lds + (r2 << 9));
    }
    asm volatile("s_waitcnt vmcnt(0)" ::: "memory");
    __syncthreads();

    f32x4 acch[2][2] = {}, accs[2][2] = {};
    const int rf0 = (wn << 5) + l15;
    const int xr  = (l15 & 7) << 3;

    #pragma unroll
    for (int kk = 0; kk < 8; ++kk) {
        const int k0 = kk << 5;
        const int kx = ((k0 + (l4 << 3)) ^ xr) << 1;
        bf16x8 av[2];
        #pragma unroll
        for (int fm = 0; fm < 2; ++fm) {
            int m = m0 + (wm << 5) + (fm << 4) + l15;
            if (m >= M) m = M - 1;
            av[fm] = *(const bf16x8*)(gated + (size_t)m * 256 + k0 + (l4 << 3));
        }
        #pragma unroll
        for (int nf = 0; nf < 2; ++nf) {
            const int rf = rf0 + (nf << 4);
            bf16x8 bh = *(const bf16x8*)(lds + (rf << 9) + kx);
            bf16x8 bs = *(const bf16x8*)(lds + ((rf + 64) << 9) + kx);
            #pragma unroll
            for (int fm = 0; fm < 2; ++fm) {
                acch[fm][nf] = __builtin_amdgcn_mfma_f32_16x16x32_bf16(
                    av[fm], bh, acch[fm][nf], 0, 0, 0);
                accs[fm][nf] = __builtin_amdgcn_mfma_f32_16x16x32_bf16(
                    av[fm], bs, accs[fm][nf], 0, 0, 0);
            }
        }
    }

    const int ms0 = (TSKIP - tb) * 16;
    const int soff = (tb - TSKIP) * 16;
    #pragma unroll
    for (int fm = 0; fm < 2; ++fm)
        #pragma unroll
        for (int nf = 0; nf < 2; ++nf) {
            int c = cb + (wn << 5) + (nf << 4) + l15;
            float bhb = sbias[c], bsb = sbias[c + 256];
            #pragma unroll
            for (int r = 0; r < 4; ++r) {
                int m = m0 + (wm << 5) + (fm << 4) + (l4 << 2) + r;
                if (m < M) {
                    size_t hi = (size_t)(m + roff1) * 256 + c;
                    float hv = hf[hi] + acch[fm][nf][r] + bhb;
                    hf[hi] = hv;
                    hb[hi] = (__bf16)hv;
                    if (m >= ms0) {
                        size_t si = (size_t)(m + soff) * 256 + c;
                        float sv = accs[fm][nf][r] + bsb;
                        if (!first) sv += skip[si];
                        skip[si] = sv;
                    }
                }
            }
        }
}

// ---------------- final
__global__ void final_kernel(const float* __restrict__ skip,
                             const float* __restrict__ loc_W,
                             const float* __restrict__ loc_b,
                             const float* __restrict__ proj_W,
                             const float* __restrict__ proj_b,
                             float* __restrict__ out)
{
    int tid = threadIdx.x;
    int w = tid >> 6, lane = tid & 63;
    int o = blockIdx.x * 4 + w;          // o = l*16 + b
    int l = o >> 4, b = o & 15;
    float4 s4 = *(const float4*)&skip[((size_t)o << 8) + (lane << 2)];
    float4 w4 = *(const float4*)&loc_W[lane << 2];
    float s = s4.x * w4.x + s4.y * w4.y + s4.z * w4.z + s4.w * w4.w;
    #pragma unroll
    for (int off = 32; off; off >>= 1) s += __shfl_down(s, off);
    if (lane == 0)
        out[b * LOUT + l] = (s + loc_b[0]) * proj_W[0] + proj_b[0];
}

extern "C" void kernel_launch(void* const* d_in, const int* in_sizes, int n_in,
                              void* d_out, int out_size, void* d_ws, size_t ws_size,
                              hipStream_t stream)
{
    const float* x_lag  = (const float*)d_in[0];
    const float* x_cov  = (const float*)d_in[1];
    const float* up_W   = (const float*)d_in[2];
    const float* up_b   = (const float*)d_in[3];
    const float* dil_w  = (const float*)d_in[4];
    const float* dil_b  = (const float*)d_in[5];
    const float* skip_w = (const float*)d_in[6];
    const float* skip_b = (const float*)d_in[7];
    const float* loc_W  = (const float*)d_in[8];
    const float* loc_b  = (const float*)d_in[9];
    const float* proj_W = (const float*)d_in[10];
    const float* proj_b = (const float*)d_in[11];
    float* out = (float*)d_out;

    unsigned char* ws = (unsigned char*)d_ws;
    float*  hf   = (float*)ws;                              // 5632*256 f32
    __bf16* hb   = (__bf16*)(ws + 5767168);                 // 5632*256 bf16
    __bf16* gated= (__bf16*)(ws + 5767168 + 2883584);       // 5632*256 bf16
    float*  skip = (float*)(ws + 5767168 + 2 * 2883584);    // 1536*256 f32
    __bf16* wT   = (__bf16*)(ws + 5767168 + 2 * 2883584 + 1572864);  // 8*512*512
    __bf16* w2   = (__bf16*)((unsigned char*)wT + 4194304); // 8*512*256

    hipLaunchKernelGGL(prep_w, dim3(12288), dim3(256), 0, stream,
                       dil_w, skip_w, wT, w2);
    hipLaunchKernelGGL(up_kernel, dim3(TBUF * NB), dim3(D), 0, stream,
                       x_lag, x_cov, up_W, up_b, hf, hb);

    for (int i = 0; i < 8; ++i) {
        int dil = 1 << i;
        int tb  = T0 + 2 * dil;
        int M   = (T_TOTAL - tb) * NB;
        int mt  = (M + 63) >> 6;
        hipLaunchKernelGGL(gate_v3, dim3(mt, 4), dim3(256), 0, stream,
                           hb, gated, wT + (size_t)i * 512 * 512,
                           dil_b + (size_t)i * 512, tb, dil, M);
        hipLaunchKernelGGL(skip_v3, dim3(mt, 4), dim3(256), 0, stream,
                           gated, w2 + (size_t)i * 512 * 256, hf, hb, skip,
                           skip_b + (size_t)i * 512, tb, M, i == 0 ? 1 : 0);
    }
    hipLaunchKernelGGL(final_kernel, dim3(LOUT * NB / 4), dim3(256), 0, stream,
                       skip, loc_W, loc_b, proj_W, proj_b, out);
}

// Round 8
// 160.243 us; speedup vs baseline: 5.2934x; 1.6535x over previous
//
#include <hip/hip_runtime.h>
#include <math.h>
#include <stdint.h>

#define T_TOTAL 2048
#define NB 16
#define D 256
#define T0 1696      // h buffer covers t in [1696, 2047]
#define TBUF 352
#define TSKIP 1952   // skip needed for t in [1952, 2047]
#define LOUT 96

typedef __bf16 bf16x8 __attribute__((ext_vector_type(8)));
typedef float f32x4 __attribute__((ext_vector_type(4)));

__device__ __forceinline__ void gload_lds16(const void* src, void* lds_dst) {
    auto g = (const __attribute__((address_space(1))) void*)(uintptr_t)src;
    auto l = (__attribute__((address_space(3))) void*)(uintptr_t)(
                 (uint32_t)(uintptr_t)lds_dst);
    __builtin_amdgcn_global_load_lds(g, l, 16, 0, 0);
}

// ---------------- fused weight prep + up-projection (one dispatch)
// wT[i][co][k] = dil_w[i][co][ci][tap], k = tap*256+ci (bf16)
// w2[i][co][ci] = skip_w[i][co][ci] (bf16)
// h[t,b,:] = concat(x_lag,x_cov) @ up_W + up_b  (f32 + bf16 copies)
__global__ __launch_bounds__(256) void prep_up(
    const float* __restrict__ dil_w, const float* __restrict__ skip_w,
    const float* __restrict__ x_lag, const float* __restrict__ x_cov,
    const float* __restrict__ up_W, const float* __restrict__ up_b,
    __bf16* __restrict__ wT, __bf16* __restrict__ w2,
    float* __restrict__ hf, __bf16* __restrict__ hb)
{
    const int g0 = blockIdx.x * 256 + threadIdx.x;
    const int NT = 2048 * 256;

    // job A: dil_w transpose, unit = (i*512+co, ci-group of 8)
    for (int u = g0; u < 8 * 512 * 32; u += NT) {
        int j = u & 31;
        int cog = u >> 5;
        const float* src = dil_w + ((size_t)cog << 9) + (j << 4);
        float4 a = *(const float4*)(src);
        float4 b = *(const float4*)(src + 4);
        float4 c = *(const float4*)(src + 8);
        float4 d = *(const float4*)(src + 12);
        bf16x8 t0 = {(__bf16)a.x, (__bf16)a.z, (__bf16)b.x, (__bf16)b.z,
                     (__bf16)c.x, (__bf16)c.z, (__bf16)d.x, (__bf16)d.z};
        bf16x8 t1 = {(__bf16)a.y, (__bf16)a.w, (__bf16)b.y, (__bf16)b.w,
                     (__bf16)c.y, (__bf16)c.w, (__bf16)d.y, (__bf16)d.w};
        *(bf16x8*)(wT + ((size_t)cog << 9) + (j << 3)) = t0;
        *(bf16x8*)(wT + ((size_t)cog << 9) + 256 + (j << 3)) = t1;
    }
    // job B: skip_w cast, 8 at a time
    for (int u = g0; u < 8 * 512 * 32; u += NT) {
        const float* src = skip_w + ((size_t)u << 3);
        float4 a = *(const float4*)(src);
        float4 b = *(const float4*)(src + 4);
        bf16x8 v = {(__bf16)a.x, (__bf16)a.y, (__bf16)a.z, (__bf16)a.w,
                    (__bf16)b.x, (__bf16)b.y, (__bf16)b.z, (__bf16)b.w};
        *(bf16x8*)(w2 + ((size_t)u << 3)) = v;
    }
    // job C: up-projection, unit = (row, channel)
    for (int u = g0; u < TBUF * NB * D; u += NT) {
        int row = u >> 8, c = u & 255;
        int tt = row >> 4, b = row & 15, t = T0 + tt;
        float acc = up_b[c] + x_lag[t * NB + b] * up_W[c];
        const float* cov = &x_cov[(t * NB + b) * 7];
        #pragma unroll
        for (int j = 0; j < 7; ++j)
            acc += cov[j] * up_W[(j + 1) * D + c];
        hf[u] = acc;
        hb[u] = (__bf16)acc;
    }
}

// ---------------- GEMM1 (dbuf, 8 waves): z=[h(t-dil),h(t)]@wT^T ; gated=tanh*sig
// grid (mt, 4); block 512 thr; wave tile 32 rows x (16f + 16g) cols
__global__ __launch_bounds__(512, 4) void gate_v4(
    const __bf16* __restrict__ hb, __bf16* __restrict__ gated,
    const __bf16* __restrict__ wTl, const float* __restrict__ gbias,
    int tb, int dil, int M)
{
    __shared__ __align__(16) unsigned char lds[49152];
    const int tid = threadIdx.x;
    const int lane = tid & 63, wid = tid >> 6;
    const int wm = wid >> 2, wn = wid & 3;
    const int l15 = lane & 15, l4 = lane >> 4;
    const int m0 = blockIdx.x << 6;
    const int cb = blockIdx.y << 6;
    const int row_s = (wid << 3) + (lane >> 3);      // staging row 0..63
    const int swz = ((lane & 7) ^ (row_s & 7)) << 3; // swizzled src elem off
    const int roff1 = (tb - T0) * 16;
    const int roff0 = roff1 - dil * 16;

    f32x4 accf[2] = {}, accg[2] = {};

    auto stage = [&](int t, int buf) {
        const int k0 = t << 6;
        const int ci0 = k0 & 255;
        const int roff = (t < 4) ? roff0 : roff1;
        unsigned char* base = lds + buf * 24576;
        int m = m0 + row_s; if (m >= M) m = M - 1;
        gload_lds16(hb + (size_t)(m + roff) * 256 + ci0 + swz,
                    base + (wid << 10));
        gload_lds16(wTl + (size_t)(cb + row_s) * 512 + k0 + swz,
                    base + 8192 + (wid << 10));
        gload_lds16(wTl + (size_t)(cb + 256 + row_s) * 512 + k0 + swz,
                    base + 16384 + (wid << 10));
    };

    stage(0, 0);
    for (int t = 0; t < 8; ++t) {
        const int buf = t & 1;
        if (t < 7) {
            stage(t + 1, buf ^ 1);
            asm volatile("s_waitcnt vmcnt(3)" ::: "memory");
        } else {
            asm volatile("s_waitcnt vmcnt(0)" ::: "memory");
        }
        __builtin_amdgcn_s_barrier();
        const unsigned char* base = lds + buf * 24576;
        __builtin_amdgcn_s_setprio(1);
        #pragma unroll
        for (int ks = 0; ks < 2; ++ks) {
            const int kb = (ks << 6) + (l4 << 4);
            bf16x8 av[2], bfv, bgv;
            #pragma unroll
            for (int fm = 0; fm < 2; ++fm) {
                int r = (wm << 5) + (fm << 4) + l15;
                av[fm] = *(const bf16x8*)(base + r * 128 + (kb ^ ((r & 7) << 4)));
            }
            {
                int n = (wn << 4) + l15;
                int o = n * 128 + (kb ^ ((n & 7) << 4));
                bfv = *(const bf16x8*)(base + 8192 + o);
                bgv = *(const bf16x8*)(base + 16384 + o);
            }
            #pragma unroll
            for (int fm = 0; fm < 2; ++fm) {
                accf[fm] = __builtin_amdgcn_mfma_f32_16x16x32_bf16(
                    av[fm], bfv, accf[fm], 0, 0, 0);
                accg[fm] = __builtin_amdgcn_mfma_f32_16x16x32_bf16(
                    av[fm], bgv, accg[fm], 0, 0, 0);
            }
        }
        __builtin_amdgcn_s_setprio(0);
        __builtin_amdgcn_s_barrier();
    }

    {
        int c = cb + (wn << 4) + l15;
        float bfb = gbias[c], bgb = gbias[c + 256];
        #pragma unroll
        for (int fm = 0; fm < 2; ++fm)
            #pragma unroll
            for (int r = 0; r < 4; ++r) {
                int m = m0 + (wm << 5) + (fm << 4) + (l4 << 2) + r;
                if (m < M) {
                    float fv = accf[fm][r] + bfb;
                    float gv = accg[fm][r] + bgb;
                    float th = 2.0f / (1.0f + __expf(-2.0f * fv)) - 1.0f;
                    float sg = 1.0f / (1.0f + __expf(-gv));
                    gated[(size_t)m * 256 + c] = (__bf16)(th * sg);
                }
            }
    }
}

// ---------------- GEMM2 (dbuf, 8 waves, tail-aware): z2 = gated @ w2^T
// h += z2[:,:256] always; skip += z2[:,256:] only for tail blocks
__global__ __launch_bounds__(512, 4) void skip_v4(
    const __bf16* __restrict__ gated, const __bf16* __restrict__ w2l,
    float* __restrict__ hf, __bf16* __restrict__ hb,
    float* __restrict__ skip, const float* __restrict__ sbias,
    int tb, int M, int first)
{
    __shared__ __align__(16) unsigned char lds[49152];
    const int tid = threadIdx.x;
    const int lane = tid & 63, wid = tid >> 6;
    const int wm = wid >> 2, wn = wid & 3;
    const int l15 = lane & 15, l4 = lane >> 4;
    const int m0 = blockIdx.x << 6;
    const int cb = blockIdx.y << 6;
    const int row_s = (wid << 3) + (lane >> 3);
    const int swz = ((lane & 7) ^ (row_s & 7)) << 3;
    const int roff1 = (tb - T0) * 16;
    const int ms0 = (TSKIP - tb) * 16;
    const bool do_s = (m0 + 64 > ms0);    // block-uniform

    f32x4 acch[2] = {}, accs[2] = {};

    auto stage = [&](int t, int buf) {
        const int k0 = t << 6;
        unsigned char* base = lds + buf * 24576;
        int m = m0 + row_s; if (m >= M) m = M - 1;
        gload_lds16(gated + (size_t)m * 256 + k0 + swz,
                    base + (wid << 10));
        gload_lds16(w2l + (size_t)(cb + row_s) * 256 + k0 + swz,
                    base + 8192 + (wid << 10));
        if (do_s)
            gload_lds16(w2l + (size_t)(cb + 256 + row_s) * 256 + k0 + swz,
                        base + 16384 + (wid << 10));
    };

    stage(0, 0);
    for (int t = 0; t < 4; ++t) {
        const int buf = t & 1;
        if (t < 3) {
            stage(t + 1, buf ^ 1);
            if (do_s) { asm volatile("s_waitcnt vmcnt(3)" ::: "memory"); }
            else      { asm volatile("s_waitcnt vmcnt(2)" ::: "memory"); }
        } else {
            asm volatile("s_waitcnt vmcnt(0)" ::: "memory");
        }
        __builtin_amdgcn_s_barrier();
        const unsigned char* base = lds + buf * 24576;
        __builtin_amdgcn_s_setprio(1);
        #pragma unroll
        for (int ks = 0; ks < 2; ++ks) {
            const int kb = (ks << 6) + (l4 << 4);
            bf16x8 av[2], bhv, bsv;
            #pragma unroll
            for (int fm = 0; fm < 2; ++fm) {
                int r = (wm << 5) + (fm << 4) + l15;
                av[fm] = *(const bf16x8*)(base + r * 128 + (kb ^ ((r & 7) << 4)));
            }
            int n = (wn << 4) + l15;
            int o = n * 128 + (kb ^ ((n & 7) << 4));
            bhv = *(const bf16x8*)(base + 8192 + o);
            #pragma unroll
            for (int fm = 0; fm < 2; ++fm)
                acch[fm] = __builtin_amdgcn_mfma_f32_16x16x32_bf16(
                    av[fm], bhv, acch[fm], 0, 0, 0);
            if (do_s) {
                bsv = *(const bf16x8*)(base + 16384 + o);
                #pragma unroll
                for (int fm = 0; fm < 2; ++fm)
                    accs[fm] = __builtin_amdgcn_mfma_f32_16x16x32_bf16(
                        av[fm], bsv, accs[fm], 0, 0, 0);
            }
        }
        __builtin_amdgcn_s_setprio(0);
        __builtin_amdgcn_s_barrier();
    }

    const int soff = (tb - TSKIP) * 16;
    {
        int c = cb + (wn << 4) + l15;
        float bhb = sbias[c], bsb = sbias[c + 256];
        #pragma unroll
        for (int fm = 0; fm < 2; ++fm)
            #pragma unroll
            for (int r = 0; r < 4; ++r) {
                int m = m0 + (wm << 5) + (fm << 4) + (l4 << 2) + r;
                if (m < M) {
                    size_t hi = (size_t)(m + roff1) * 256 + c;
                    float hv = hf[hi] + acch[fm][r] + bhb;
                    hf[hi] = hv;
                    hb[hi] = (__bf16)hv;
                    if (do_s && m >= ms0) {
                        size_t si = (size_t)(m + soff) * 256 + c;
                        float sv = accs[fm][r] + bsb;
                        if (!first) sv += skip[si];
                        skip[si] = sv;
                    }
                }
            }
    }
}

// ---------------- final
__global__ void final_kernel(const float* __restrict__ skip,
                             const float* __restrict__ loc_W,
                             const float* __restrict__ loc_b,
                             const float* __restrict__ proj_W,
                             const float* __restrict__ proj_b,
                             float* __restrict__ out)
{
    int tid = threadIdx.x;
    int w = tid >> 6, lane = tid & 63;
    int o = blockIdx.x * 4 + w;          // o = l*16 + b
    int l = o >> 4, b = o & 15;
    float4 s4 = *(const float4*)&skip[((size_t)o << 8) + (lane << 2)];
    float4 w4 = *(const float4*)&loc_W[lane << 2];
    float s = s4.x * w4.x + s4.y * w4.y + s4.z * w4.z + s4.w * w4.w;
    #pragma unroll
    for (int off = 32; off; off >>= 1) s += __shfl_down(s, off);
    if (lane == 0)
        out[b * LOUT + l] = (s + loc_b[0]) * proj_W[0] + proj_b[0];
}

extern "C" void kernel_launch(void* const* d_in, const int* in_sizes, int n_in,
                              void* d_out, int out_size, void* d_ws, size_t ws_size,
                              hipStream_t stream)
{
    const float* x_lag  = (const float*)d_in[0];
    const float* x_cov  = (const float*)d_in[1];
    const float* up_W   = (const float*)d_in[2];
    const float* up_b   = (const float*)d_in[3];
    const float* dil_w  = (const float*)d_in[4];
    const float* dil_b  = (const float*)d_in[5];
    const float* skip_w = (const float*)d_in[6];
    const float* skip_b = (const float*)d_in[7];
    const float* loc_W  = (const float*)d_in[8];
    const float* loc_b  = (const float*)d_in[9];
    const float* proj_W = (const float*)d_in[10];
    const float* proj_b = (const float*)d_in[11];
    float* out = (float*)d_out;

    unsigned char* ws = (unsigned char*)d_ws;
    float*  hf   = (float*)ws;                              // 5632*256 f32
    __bf16* hb   = (__bf16*)(ws + 5767168);                 // 5632*256 bf16
    __bf16* gated= (__bf16*)(ws + 5767168 + 2883584);       // 5632*256 bf16
    float*  skip = (float*)(ws + 5767168 + 2 * 2883584);    // 1536*256 f32
    __bf16* wT   = (__bf16*)(ws + 5767168 + 2 * 2883584 + 1572864);  // 8*512*512
    __bf16* w2   = (__bf16*)((unsigned char*)wT + 4194304); // 8*512*256

    hipLaunchKernelGGL(prep_up, dim3(2048), dim3(256), 0, stream,
                       dil_w, skip_w, x_lag, x_cov, up_W, up_b, wT, w2, hf, hb);

    for (int i = 0; i < 8; ++i) {
        int dil = 1 << i;
        int tb  = T0 + 2 * dil;
        int M   = (T_TOTAL - tb) * NB;
        int mt  = (M + 63) >> 6;
        hipLaunchKernelGGL(gate_v4, dim3(mt, 4), dim3(512), 0, stream,
                           hb, gated, wT + (size_t)i * 512 * 512,
                           dil_b + (size_t)i * 512, tb, dil, M);
        hipLaunchKernelGGL(skip_v4, dim3(mt, 4), dim3(512), 0, stream,
                           gated, w2 + (size_t)i * 512 * 256, hf, hb, skip,
                           skip_b + (size_t)i * 512, tb, M, i == 0 ? 1 : 0);
    }
    hipLaunchKernelGGL(final_kernel, dim3(LOUT * NB / 4), dim3(256), 0, stream,
                       skip, loc_W, loc_b, proj_W, proj_b, out);
}